// Round 3
// baseline (28630.814 us; speedup 1.0000x reference)
//
#include <hip/hip_runtime.h>
#include <cstddef>

// Problem constants
#define S_ 512
#define B_ 64
#define I_ 256
#define H_ 1024

// ---------------------------------------------------------------------------
// Transpose: out[c*R + r] = in[r*C + c]  (used for Wx only)
// ---------------------------------------------------------------------------
__global__ __launch_bounds__(256) void transpose_k(const float* __restrict__ in,
                                                   float* __restrict__ out,
                                                   int R, int C) {
  __shared__ float t[32][33];
  int c0 = blockIdx.x * 32, r0 = blockIdx.y * 32;
  int x = threadIdx.x & 31, y = threadIdx.x >> 5;
  for (int i = 0; i < 32; i += 8)
    t[y + i][x] = in[(size_t)(r0 + y + i) * C + (c0 + x)];
  __syncthreads();
  for (int i = 0; i < 32; i += 8)
    out[(size_t)(c0 + y + i) * R + (r0 + x)] = t[x][y + i];
}

// ---------------------------------------------------------------------------
// xproj: out[m*H + j] = dot(x[m, :], WxT[:, j]) + bx[j]   (writes into d_out)
// ---------------------------------------------------------------------------
__global__ __launch_bounds__(256) void xproj_kernel(const float* __restrict__ x,
                                                    const float* __restrict__ WxT,
                                                    const float* __restrict__ bx,
                                                    float* __restrict__ out) {
  __shared__ float xs[4][I_];
  int tid = threadIdx.x;
  int j = blockIdx.x * 256 + tid;
  size_t m0 = (size_t)blockIdx.y * 4;
  const float* xrow = x + m0 * I_;
  for (int r = 0; r < 4; ++r) xs[r][tid] = xrow[(size_t)r * I_ + tid];
  __syncthreads();

  float bj = bx[j];
  float a0 = bj, a1 = bj, a2 = bj, a3 = bj;
  const float* wp = WxT + j;
  for (int k = 0; k < I_; k += 4) {
    float w0 = wp[(size_t)(k + 0) * H_];
    float w1 = wp[(size_t)(k + 1) * H_];
    float w2 = wp[(size_t)(k + 2) * H_];
    float w3 = wp[(size_t)(k + 3) * H_];
    float4 v0 = *(const float4*)&xs[0][k];
    float4 v1 = *(const float4*)&xs[1][k];
    float4 v2 = *(const float4*)&xs[2][k];
    float4 v3 = *(const float4*)&xs[3][k];
    a0 += w0 * v0.x + w1 * v0.y + w2 * v0.z + w3 * v0.w;
    a1 += w0 * v1.x + w1 * v1.y + w2 * v1.z + w3 * v1.w;
    a2 += w0 * v2.x + w1 * v2.y + w2 * v2.z + w3 * v2.w;
    a3 += w0 * v3.x + w1 * v3.y + w2 * v3.z + w3 * v3.w;
  }
  out[(m0 + 0) * H_ + j] = a0;
  out[(m0 + 1) * H_ + j] = a1;
  out[(m0 + 2) * H_ + j] = a2;
  out[(m0 + 3) * H_ + j] = a3;
}

// ---------------------------------------------------------------------------
// Persistent RNN with weights resident in LDS and p2p flag sync.
//
// Grid = 256 blocks = 32 j-tiles x 8 batch-groups.  bt = blockIdx.x & 7 so
// that each batch-group's 32 blocks land round-robin on the same XCD
// (perf heuristic only; correctness is device-scope).
//
// Block (jt, bt), 512 threads = 8 waves:
//   - Wlds[32 j][1024 k] fp32 = 128 KB, staged once, resident for all steps.
//   - per step: wait flag[t-1][bt]==32, stage h_{t-1}[8 b] from global in two
//     512-k halves (16 KB LDS), GEMM with 16-way k-split (thread = (j, kslot),
//     8 batch accumulators), cross-kslot reduce via LDS, + bh + xproj (read
//     in-place from d_out), tanh, write h_t to d_out and the parity h buffer,
//     release-fence, fetch_add flag[t][bt].
//   - batches are independent => zero cross-group communication; no grid sync.
// LDS total = 131072 + 18432 = 149504 B (< 160 KB, 1 block/CU).
// ---------------------------------------------------------------------------
__global__ __launch_bounds__(512, 1) void rnn_flag(
    const float* __restrict__ Wh, const float* __restrict__ bh,
    float* __restrict__ out, float* __restrict__ hbuf,  // [2][B_][H_]
    int* __restrict__ flags) {                          // [S_][8]
  __shared__ float Wlds[32 * 1024];  // [j][k]
  __shared__ float scr[4608];        // union: h-stage 8x512 (4096 f) / red 16x32x9

  const int tid = threadIdx.x;
  const int bt = blockIdx.x & 7;   // batch group (XCD-affine)
  const int jt = blockIdx.x >> 3;  // j tile [0,32)
  const int jg = jt * 32;
  const int bg = bt * 8;

  // stage Wh[jg..jg+32][:] -> Wlds (coalesced float4)
  {
    const float4* src = (const float4*)(Wh + (size_t)jg * H_);
    float4* dst = (float4*)Wlds;
    for (int i = tid; i < 32 * (H_ / 4); i += 512) dst[i] = src[i];
  }

  const int j = tid & 31;
  const int ks = tid >> 5;  // k-slot [0,16)

  // reducer mapping (tid < 256)
  const int j_r = tid & 31;
  const int b_r = tid >> 5;  // [0,8) when tid<256
  float bhv = (tid < 256) ? bh[jg + j_r] : 0.f;

  __syncthreads();

  for (int t = 0; t < S_; ++t) {
    float acc[8] = {0.f, 0.f, 0.f, 0.f, 0.f, 0.f, 0.f, 0.f};

    if (t > 0) {
      // acquire: wait for all 32 producers of h_{t-1} in this batch group
      if (tid == 0) {
        while (__hip_atomic_load(&flags[(t - 1) * 8 + bt], __ATOMIC_ACQUIRE,
                                 __HIP_MEMORY_SCOPE_AGENT) < 32)
          __builtin_amdgcn_s_sleep(1);
      }
      __syncthreads();

      const float* hsrc = hbuf + ((size_t)((t - 1) & 1) * B_ + bg) * H_;
      for (int half = 0; half < 2; ++half) {
        // stage h[8 b][half*512 .. +512) -> scr[b*512 + kk]
        {
          const float4* s4 = (const float4*)hsrc;
          float4* d4 = (float4*)scr;
          for (int i = tid; i < 8 * 128; i += 512) {
            int b = i >> 7, kq = i & 127;
            d4[b * 128 + kq] = s4[b * 256 + half * 128 + kq];
          }
        }
        __syncthreads();
        // GEMM: thread covers k in [half*512 + ks*32, +32)
        const float* wrow = Wlds + j * 1024 + half * 512 + ks * 32;
#pragma unroll
        for (int c = 0; c < 8; ++c) {
          float4 w = *(const float4*)(wrow + c * 4);
          int kih = ks * 32 + c * 4;
#pragma unroll
          for (int b = 0; b < 8; ++b) {
            float4 h4 = *(const float4*)(scr + b * 512 + kih);
            acc[b] += w.x * h4.x + w.y * h4.y + w.z * h4.z + w.w * h4.w;
          }
        }
        __syncthreads();  // scr reused (next half / reduce)
      }
      // partials: red[ks][j][b], row stride 9 to break bank conflicts
      for (int b = 0; b < 8; ++b) scr[ks * 288 + j * 9 + b] = acc[b];
      __syncthreads();
    }

    // reduce + bias + xproj + tanh (first 256 threads: one (j,b) each)
    if (tid < 256) {
      size_t oidx = (size_t)t * B_ * H_ + (size_t)(bg + b_r) * H_ + jg + j_r;
      float z = bhv + out[oidx];  // xproj read in place
      if (t > 0) {
#pragma unroll
        for (int kk = 0; kk < 16; ++kk) z += scr[kk * 288 + j_r * 9 + b_r];
      }
      float h = tanhf(z);
      out[oidx] = h;
      hbuf[((size_t)(t & 1) * B_ + bg + b_r) * H_ + jg + j_r] = h;
      if (t == S_ - 1)
        out[(size_t)S_ * B_ * H_ + (size_t)(bg + b_r) * H_ + jg + j_r] = h;
    }

    // release: make h_t visible, then bump this group's flag
    __threadfence();
    __syncthreads();
    if (tid == 0)
      __hip_atomic_fetch_add(&flags[t * 8 + bt], 1, __ATOMIC_RELEASE,
                             __HIP_MEMORY_SCOPE_AGENT);
  }
}

// ---------------------------------------------------------------------------
// ws layout (bytes):
//   WxT   : I_*H_*4          = 1 MB
//   hbuf  : 2*B_*H_*4        = 512 KB
//   flags : S_*8*4           = 16 KB
// ---------------------------------------------------------------------------
extern "C" void kernel_launch(void* const* d_in, const int* in_sizes, int n_in,
                              void* d_out, int out_size, void* d_ws, size_t ws_size,
                              hipStream_t stream) {
  const float* x  = (const float*)d_in[0];
  const float* Wx = (const float*)d_in[1];
  const float* bx = (const float*)d_in[2];
  const float* Wh = (const float*)d_in[3];
  const float* bh = (const float*)d_in[4];
  float* out = (float*)d_out;

  float* WxT  = (float*)d_ws;
  float* hbuf = WxT + (size_t)I_ * H_;
  int* flags  = (int*)(hbuf + (size_t)2 * B_ * H_);

  // flags must start at 0 every launch (ws is re-poisoned before each call)
  hipMemsetAsync(flags, 0, (size_t)S_ * 8 * sizeof(int), stream);

  hipLaunchKernelGGL(transpose_k, dim3(I_ / 32, H_ / 32), dim3(256), 0, stream,
                     Wx, WxT, H_, I_);
  hipLaunchKernelGGL(xproj_kernel, dim3(H_ / 256, (S_ * B_) / 4), dim3(256), 0, stream,
                     x, WxT, bx, out);

  // cooperative launch only for the co-residency guarantee (no grid.sync used)
  void* args[] = {(void*)&Wh, (void*)&bh, (void*)&out, (void*)&hbuf, (void*)&flags};
  hipLaunchCooperativeKernel((void*)rnn_flag, dim3(256), dim3(512), args, 0, stream);
}